// Round 16
// baseline (161.029 us; speedup 1.0000x reference)
//
#include <hip/hip_runtime.h>
#include <hip/hip_bf16.h>

// Problem constants (B=1)
#define L_SEQ   2048
#define D_MODEL 512
#define D_INNER 1024
#define D_STATE 16
#define DT_RANK 32

typedef unsigned short u16;
typedef short bf16x8 __attribute__((ext_vector_type(8)));
typedef float f32x4  __attribute__((ext_vector_type(4)));
typedef unsigned short u16x8 __attribute__((ext_vector_type(8)));

__device__ __forceinline__ u16 f2bf(float f) {
    union { float f; unsigned u; } x; x.f = f;
    unsigned r = x.u + 0x7FFFu + ((x.u >> 16) & 1u);
    return (u16)(r >> 16);
}

__device__ __forceinline__ void gload_lds16(const void* g, void* l) {
    __builtin_amdgcn_global_load_lds((const __attribute__((address_space(1))) void*)g,
                                     (__attribute__((address_space(3))) void*)l, 16, 0, 0);
}

// ---------------------------------------------------------------------------
// bf16 MFMA GEMM (NT):  C[m][n] = sum_k A[m*K+k]*B[n*K+k], C f32.  (verified)
// ---------------------------------------------------------------------------
template<int BM, int BN>
__global__ __launch_bounds__(256)
void gemm_mfma_nt(const u16* __restrict__ A, const u16* __restrict__ B,
                  float* __restrict__ C, int M, int N, int K, int ldc) {
    constexpr int FM = BM / 32;
    constexpr int FN = BN / 32;
    __shared__ u16 lA[BM * 64];
    __shared__ u16 lB[BN * 64];

    const int tid  = threadIdx.x;
    const int lane = tid & 63;
    const int w    = tid >> 6;
    const int wr   = w >> 1, wc = w & 1;
    const int m0 = blockIdx.y * BM;
    const int n0 = blockIdx.x * BN;

    f32x4 acc[FM][FN];
#pragma unroll
    for (int m = 0; m < FM; m++)
#pragma unroll
        for (int n = 0; n < FN; n++) acc[m][n] = (f32x4){0.f, 0.f, 0.f, 0.f};

    int offA[FM][2], offB[FN][2];
#pragma unroll
    for (int m = 0; m < FM; m++) {
        int r = wr * (BM / 2) + m * 16 + (lane & 15);
#pragma unroll
        for (int s = 0; s < 2; s++) {
            int kb = s * 4 + (lane >> 4);
            offA[m][s] = r * 128 + ((kb ^ (r & 7)) << 4);
        }
    }
#pragma unroll
    for (int n = 0; n < FN; n++) {
        int r = wc * (BN / 2) + n * 16 + (lane & 15);
#pragma unroll
        for (int s = 0; s < 2; s++) {
            int kb = s * 4 + (lane >> 4);
            offB[n][s] = r * 128 + ((kb ^ (r & 7)) << 4);
        }
    }

    const int ldsbase = (tid & 192) * 16;

    for (int k0 = 0; k0 < K; k0 += 64) {
        __syncthreads();
#pragma unroll
        for (int i = 0; i < BM / 32; i++) {
            int o = i * 4096 + tid * 16;
            int r = o >> 7;
            int kb = ((o >> 4) & 7) ^ (r & 7);
            gload_lds16(A + (size_t)(m0 + r) * K + k0 + kb * 8,
                        (char*)lA + i * 4096 + ldsbase);
        }
#pragma unroll
        for (int i = 0; i < BN / 32; i++) {
            int o = i * 4096 + tid * 16;
            int r = o >> 7;
            int kb = ((o >> 4) & 7) ^ (r & 7);
            gload_lds16(B + (size_t)(n0 + r) * K + k0 + kb * 8,
                        (char*)lB + i * 4096 + ldsbase);
        }
        __syncthreads();

#pragma unroll
        for (int s = 0; s < 2; s++) {
            bf16x8 av[FM], bv[FN];
#pragma unroll
            for (int m = 0; m < FM; m++)
                av[m] = *(const bf16x8*)((const char*)lA + offA[m][s]);
#pragma unroll
            for (int n = 0; n < FN; n++)
                bv[n] = *(const bf16x8*)((const char*)lB + offB[n][s]);
#pragma unroll
            for (int m = 0; m < FM; m++)
#pragma unroll
                for (int n = 0; n < FN; n++)
                    acc[m][n] = __builtin_amdgcn_mfma_f32_16x16x32_bf16(
                        av[m], bv[n], acc[m][n], 0, 0, 0);
        }
    }

    const int rb = (lane >> 4) * 4;
    const int cb = lane & 15;
#pragma unroll
    for (int m = 0; m < FM; m++)
#pragma unroll
        for (int n = 0; n < FN; n++) {
            int col = n0 + wc * (BN / 2) + n * 16 + cb;
#pragma unroll
            for (int j = 0; j < 4; j++) {
                int row = m0 + wr * (BM / 2) + m * 16 + rb + j;
                C[(size_t)row * ldc + col] = acc[m][n][j];
            }
        }
}

// ---------------------------------------------------------------------------
// Fused f32->bf16 cast of x, in_proj_w, out_proj_w.
// ---------------------------------------------------------------------------
__global__ __launch_bounds__(256)
void cast3_kernel(const float* __restrict__ x, const float* __restrict__ w1,
                  const float* __restrict__ w2,
                  u16* __restrict__ xb, u16* __restrict__ w1b, u16* __restrict__ w2b) {
    int g = blockIdx.x * 256 + threadIdx.x;
    const float* src; u16* dst; int off;
    if (g < 131072)      { src = x;  dst = xb;  off = g; }
    else if (g < 262144) { src = w1; dst = w1b; off = g - 131072; }
    else                 { src = w2; dst = w2b; off = g - 262144; }
    float4 v0 = ((const float4*)src)[off * 2];
    float4 v1 = ((const float4*)src)[off * 2 + 1];
    u16x8 r;
    r[0] = f2bf(v0.x); r[1] = f2bf(v0.y); r[2] = f2bf(v0.z); r[3] = f2bf(v0.w);
    r[4] = f2bf(v1.x); r[5] = f2bf(v1.y); r[6] = f2bf(v1.z); r[7] = f2bf(v1.w);
    *(u16x8*)(dst + (size_t)off * 8) = r;
}

// ---------------------------------------------------------------------------
// Causal depthwise conv (4 taps) + SiLU on T layout.
// ---------------------------------------------------------------------------
__global__ __launch_bounds__(256)
void conv_rows_kernel(const float* __restrict__ xzT,
                      const float* __restrict__ w,   // [1024][4]
                      const float* __restrict__ b,   // [1024]
                      float* __restrict__ xpcT) {
    const int d = blockIdx.y;
    const int l = blockIdx.x * 1024 + threadIdx.x * 4;
    const float4 wv = ((const float4*)w)[d];
    const float bias = b[d];
    const float* row = xzT + (size_t)d * L_SEQ;

    float4 cur  = *(const float4*)(row + l);
    float4 prev = (l == 0) ? make_float4(0.f, 0.f, 0.f, 0.f)
                           : *(const float4*)(row + l - 4);
    float e1 = prev.y, e2 = prev.z, e3 = prev.w;
    float e4 = cur.x, e5 = cur.y, e6 = cur.z, e7 = cur.w;
    float4 r;
    r.x = bias + wv.x * e1 + wv.y * e2 + wv.z * e3 + wv.w * e4;
    r.y = bias + wv.x * e2 + wv.y * e3 + wv.z * e4 + wv.w * e5;
    r.z = bias + wv.x * e3 + wv.y * e4 + wv.z * e5 + wv.w * e6;
    r.w = bias + wv.x * e4 + wv.y * e5 + wv.z * e6 + wv.w * e7;
    r.x = r.x / (1.f + __expf(-r.x));
    r.y = r.y / (1.f + __expf(-r.y));
    r.z = r.z / (1.f + __expf(-r.z));
    r.w = r.w / (1.f + __expf(-r.w));
    *(float4*)(xpcT + (size_t)d * L_SEQ + l) = r;
}

// ---------------------------------------------------------------------------
// x_proj on T layout.
// ---------------------------------------------------------------------------
__global__ __launch_bounds__(256)
void xproj_kernel(const float* __restrict__ xpcT,
                  const float* __restrict__ xw,    // [64][1024]
                  float* __restrict__ xdblT) {     // [64][2048]
    const int tid  = threadIdx.x;
    const int part = tid >> 7;
    const int e    = (tid >> 1) & 63;
    const int lc   = tid & 1;
    const int l0   = blockIdx.x * 8;

    const float* wrow = xw + (size_t)e * 1024 + part * 512;
    const float* xcol = xpcT + (size_t)part * 512 * L_SEQ + l0 + lc * 4;

    f32x4 acc = {0.f, 0.f, 0.f, 0.f};
#pragma unroll 4
    for (int k = 0; k < 512; k += 4) {
        float4 wv = *(const float4*)(wrow + k);
        f32x4 x0 = *(const f32x4*)(xcol + (size_t)(k + 0) * L_SEQ);
        f32x4 x1 = *(const f32x4*)(xcol + (size_t)(k + 1) * L_SEQ);
        f32x4 x2 = *(const f32x4*)(xcol + (size_t)(k + 2) * L_SEQ);
        f32x4 x3 = *(const f32x4*)(xcol + (size_t)(k + 3) * L_SEQ);
        acc += wv.x * x0 + wv.y * x1 + wv.z * x2 + wv.w * x3;
    }

    __shared__ f32x4 red[128];
    if (part == 1) red[(e << 1) | lc] = acc;
    __syncthreads();
    if (part == 0) {
        acc += red[(e << 1) | lc];
        *(f32x4*)(xdblT + (size_t)e * L_SEQ + l0 + lc * 4) = acc;
    }
}

// ---------------------------------------------------------------------------
// dt_proj + softplus (T layout).
// ---------------------------------------------------------------------------
__global__ __launch_bounds__(256)
void deltaT_kernel(const float* __restrict__ xdblT,
                   const float* __restrict__ dtw,   // [1024][32]
                   const float* __restrict__ dtb,
                   float* __restrict__ deltaT) {    // [1024][2048]
    const int tid = threadIdx.x;
    const int d0 = blockIdx.x * 64;
    const int l0 = blockIdx.y * 128;

    __shared__ float sx[32][128];
#pragma unroll
    for (int it = 0; it < 4; it++) {
        int idx = it * 256 + tid;
        int r  = idx >> 5;
        int c4 = (idx & 31) * 4;
        *(float4*)&sx[r][c4] = *(const float4*)(xdblT + (size_t)r * 2048 + l0 + c4);
    }

    const int dl = tid >> 2;
    const int lg = tid & 3;
    const int d  = d0 + dl;
    float wreg[32];
#pragma unroll
    for (int r4 = 0; r4 < 32; r4 += 4)
        *(float4*)&wreg[r4] = *(const float4*)(dtw + (size_t)d * 32 + r4);
    const float bias = dtb[d];
    __syncthreads();

#pragma unroll
    for (int j = 0; j < 8; j++) {
        float4 a = make_float4(bias, bias, bias, bias);
        const int col = j * 16 + lg * 4;
#pragma unroll
        for (int r = 0; r < 32; r++) {
            float4 v = *(const float4*)&sx[r][col];
            a.x = fmaf(wreg[r], v.x, a.x);
            a.y = fmaf(wreg[r], v.y, a.y);
            a.z = fmaf(wreg[r], v.z, a.z);
            a.w = fmaf(wreg[r], v.w, a.w);
        }
        float4 o;
        o.x = fmaxf(a.x, 0.f) + log1pf(expf(-fabsf(a.x)));
        o.y = fmaxf(a.y, 0.f) + log1pf(expf(-fabsf(a.y)));
        o.z = fmaxf(a.z, 0.f) + log1pf(expf(-fabsf(a.z)));
        o.w = fmaxf(a.w, 0.f) + log1pf(expf(-fabsf(a.w)));
        *(float4*)(deltaT + (size_t)d * 2048 + l0 + col) = o;
    }
}

// ---------------------------------------------------------------------------
// Chunked selective scan v16: R12 scaffold (1024 thr, 2 ch/block, 512 blocks,
// 32 chunks x 64 steps, deferred-gate epilogue) with the recurrence rewritten
// in the reference's own cumsum form:
//   h_t = cA_t * S_t,  S_t = sum u_tau,  u = inp/(cAprev+1e-8),
//   cA_t = exp(lsum + running clipped-log)
// The per-step serial chain collapses from ~10 dependent ops (exp/rcp/fma)
// to pure f32 adds (2 per 4-step quad via in-quad parallel prefix).  Exact
// algebraic match to R12's recurrence (expansion verified).  Phase-B combine
// becomes a U-prefix sum (sP/sH eliminated).
// ---------------------------------------------------------------------------
#define NCHUNK 32

__global__ __launch_bounds__(1024)
void scan_kernel(const float* __restrict__ deltaT,
                 const float* __restrict__ xpcT,
                 const float* __restrict__ xzT,    // z rows at 1024+d
                 const float* __restrict__ xdblT,  // rows 32..47=B_T, 48..63=C_T
                 const float* __restrict__ A_log, const float* __restrict__ Dv,
                 u16* __restrict__ ypreT) {
    const int tid   = threadIdx.x;
    const int lane  = tid & 63;
    const int chunk = ((tid >> 6) << 1) | (lane >> 5);   // 0..31
    const int dl    = (lane >> 4) & 1;
    const int n     = lane & 15;
    const int li    = (dl << 4) | n;
    const int d0    = blockIdx.x * 2;
    const int d     = d0 + dl;
    const int lb    = chunk * 64;

    const float Aneg = -__expf(A_log[d * D_STATE + n]);

    const f32x4* dT4 = (const f32x4*)(deltaT + (size_t)d * L_SEQ + lb);
    const f32x4* xT4 = (const f32x4*)(xpcT   + (size_t)d * L_SEQ + lb);
    const f32x4* bT4 = (const f32x4*)(xdblT + (size_t)(32 + n) * L_SEQ + lb);
    const f32x4* cT4 = (const f32x4*)(xdblT + (size_t)(48 + n) * L_SEQ + lb);

    __shared__ float sLog[NCHUNK][32];
    __shared__ float sU[NCHUNK][32];
    __shared__ float s_p[2][NCHUNK][68];   // staggered rows (2-way = free)

    const float clipLog = -13.815511f;   // logf(1e-6f)
    const float EPS = 1e-8f;

    // ---- Phase A: chunk log-decay sum (4 independent partials) ----
    float sa0 = 0.f, sa1 = 0.f, sa2 = 0.f, sa3 = 0.f;
    for (int i = 0; i < 16; i++) {
        f32x4 d4 = dT4[i];
        sa0 += fmaxf(d4[0] * Aneg, clipLog);
        sa1 += fmaxf(d4[1] * Aneg, clipLog);
        sa2 += fmaxf(d4[2] * Aneg, clipLog);
        sa3 += fmaxf(d4[3] * Aneg, clipLog);
    }
    sLog[chunk][li] = (sa0 + sa1) + (sa2 + sa3);
    __syncthreads();

    float lsum = 0.f;
    for (int v = 0; v < chunk; v++) lsum += sLog[v][li];

    // ---- Phase B: chunk U sum (u = inp/(cAprev+eps)), carry chain = 1 add/quad ----
    {
        float carry = lsum;
        float ec = __expf(carry);          // cA before first step of chunk
        float U0 = 0.f, U1 = 0.f, U2 = 0.f, U3 = 0.f;
        for (int i = 0; i < 16; i++) {
            f32x4 d4 = dT4[i], x4 = xT4[i], b4 = bT4[i];
            float l0 = fmaxf(d4[0] * Aneg, clipLog);
            float l1 = fmaxf(d4[1] * Aneg, clipLog);
            float l2 = fmaxf(d4[2] * Aneg, clipLog);
            float l3 = fmaxf(d4[3] * Aneg, clipLog);
            float t01 = l0 + l1;
            float p0 = l0, p1 = t01, p2 = t01 + l2, p3 = t01 + (l2 + l3);
            float ca0 = __expf(carry + p0);
            float ca1 = __expf(carry + p1);
            float ca2 = __expf(carry + p2);
            float ca3 = __expf(carry + p3);
            float i0 = d4[0] * b4[0] * x4[0];
            float i1 = d4[1] * b4[1] * x4[1];
            float i2 = d4[2] * b4[2] * x4[2];
            float i3 = d4[3] * b4[3] * x4[3];
            U0 += i0 * __builtin_amdgcn_rcpf(ec  + EPS);
            U1 += i1 * __builtin_amdgcn_rcpf(ca0 + EPS);
            U2 += i2 * __builtin_amdgcn_rcpf(ca1 + EPS);
            U3 += i3 * __builtin_amdgcn_rcpf(ca2 + EPS);
            carry += p3;
            ec = ca3;
        }
        sU[chunk][li] = (U0 + U1) + (U2 + U3);
    }
    __syncthreads();

    float Sc = 0.f;
    for (int v = 0; v < chunk; v++) Sc += sU[v][li];

    // ---- Phase C: h = cA*S, carry chains = 2 adds/quad; shfl reduce ----
    {
        float carry = lsum;
        float ec = __expf(carry);
        for (int i = 0; i < 16; i++) {
            f32x4 d4 = dT4[i], x4 = xT4[i], b4 = bT4[i], c4 = cT4[i];
            float l0 = fmaxf(d4[0] * Aneg, clipLog);
            float l1 = fmaxf(d4[1] * Aneg, clipLog);
            float l2 = fmaxf(d4[2] * Aneg, clipLog);
            float l3 = fmaxf(d4[3] * Aneg, clipLog);
            float t01 = l0 + l1;
            float p0 = l0, p1 = t01, p2 = t01 + l2, p3 = t01 + (l2 + l3);
            float ca0 = __expf(carry + p0);
            float ca1 = __expf(carry + p1);
            float ca2 = __expf(carry + p2);
            float ca3 = __expf(carry + p3);
            float i0 = d4[0] * b4[0] * x4[0];
            float i1 = d4[1] * b4[1] * x4[1];
            float i2 = d4[2] * b4[2] * x4[2];
            float i3 = d4[3] * b4[3] * x4[3];
            float u0 = i0 * __builtin_amdgcn_rcpf(ec  + EPS);
            float u1 = i1 * __builtin_amdgcn_rcpf(ca0 + EPS);
            float u2 = i2 * __builtin_amdgcn_rcpf(ca1 + EPS);
            float u3 = i3 * __builtin_amdgcn_rcpf(ca2 + EPS);
            float q01 = u0 + u1;
            float s0 = u0, s1 = q01, s2 = q01 + u2, s3 = q01 + (u2 + u3);
            float h0 = ca0 * (Sc + s0);
            float h1 = ca1 * (Sc + s1);
            float h2 = ca2 * (Sc + s2);
            float h3 = ca3 * (Sc + s3);
            float pv0 = h0 * c4[0], pv1 = h1 * c4[1];
            float pv2 = h2 * c4[2], pv3 = h3 * c4[3];
            pv0 += __shfl_xor(pv0, 1); pv0 += __shfl_xor(pv0, 2);
            pv0 += __shfl_xor(pv0, 4); pv0 += __shfl_xor(pv0, 8);
            pv1 += __shfl_xor(pv1, 1); pv1 += __shfl_xor(pv1, 2);
            pv1 += __shfl_xor(pv1, 4); pv1 += __shfl_xor(pv1, 8);
            pv2 += __shfl_xor(pv2, 1); pv2 += __shfl_xor(pv2, 2);
            pv2 += __shfl_xor(pv2, 4); pv2 += __shfl_xor(pv2, 8);
            pv3 += __shfl_xor(pv3, 1); pv3 += __shfl_xor(pv3, 2);
            pv3 += __shfl_xor(pv3, 4); pv3 += __shfl_xor(pv3, 8);
            if (n == 0) {
                s_p[dl][chunk][4 * i + 0] = pv0;
                s_p[dl][chunk][4 * i + 1] = pv1;
                s_p[dl][chunk][4 * i + 2] = pv2;
                s_p[dl][chunk][4 * i + 3] = pv3;
            }
            Sc += s3;
            carry += p3;
            ec = ca3;
        }
    }
    __syncthreads();

    // ---- Epilogue (all lanes, vectorized): y = (p + x*D) * silu(z) ----
    {
        const int rdl = tid >> 9;
        const int pos = (tid & 511) * 4;
        const int ck = pos >> 6, off = pos & 63;
        const float Ddr = Dv[d0 + rdl];
        f32x4 p4 = *(const f32x4*)&s_p[rdl][ck][off];
        f32x4 x4 = *(const f32x4*)(xpcT + (size_t)(d0 + rdl) * L_SEQ + pos);
        f32x4 z4 = *(const f32x4*)(xzT + (size_t)(1024 + d0 + rdl) * L_SEQ + pos);
        float y0 = (p4[0] + x4[0] * Ddr) * (z4[0] * __builtin_amdgcn_rcpf(1.f + __expf(-z4[0])));
        float y1 = (p4[1] + x4[1] * Ddr) * (z4[1] * __builtin_amdgcn_rcpf(1.f + __expf(-z4[1])));
        float y2 = (p4[2] + x4[2] * Ddr) * (z4[2] * __builtin_amdgcn_rcpf(1.f + __expf(-z4[2])));
        float y3 = (p4[3] + x4[3] * Ddr) * (z4[3] * __builtin_amdgcn_rcpf(1.f + __expf(-z4[3])));
        ushort4 o;
        o.x = f2bf(y0); o.y = f2bf(y1); o.z = f2bf(y2); o.w = f2bf(y3);
        *(ushort4*)(ypreT + (size_t)(d0 + rdl) * L_SEQ + pos) = o;
    }
}

// ---------------------------------------------------------------------------
// bf16 64x64 tile transpose: ypreT[1024 d][2048 l] -> ypre[2048 l][1024 d]
// ---------------------------------------------------------------------------
__global__ __launch_bounds__(256)
void trans_bf16_kernel(const u16* __restrict__ src, u16* __restrict__ dst) {
    __shared__ u16 t[64][72];
    const int d0 = blockIdx.x * 64, l0 = blockIdx.y * 64;
    const int r = threadIdx.x >> 3;
    const int c = (threadIdx.x & 7) * 8;
#pragma unroll
    for (int rr = r; rr < 64; rr += 32)
        *(u16x8*)&t[rr][c] = *(const u16x8*)(src + (size_t)(d0 + rr) * L_SEQ + l0 + c);
    __syncthreads();
#pragma unroll
    for (int rr = r; rr < 64; rr += 32) {
        u16x8 v;
#pragma unroll
        for (int j = 0; j < 8; j++) v[j] = t[c + j][rr];
        *(u16x8*)(dst + (size_t)(l0 + rr) * D_INNER + d0 + c) = v;
    }
}

// ---------------------------------------------------------------------------
extern "C" void kernel_launch(void* const* d_in, const int* in_sizes, int n_in,
                              void* d_out, int out_size, void* d_ws, size_t ws_size,
                              hipStream_t stream) {
    const float* x          = (const float*)d_in[0];
    const float* in_proj_w  = (const float*)d_in[1];
    const float* conv_w     = (const float*)d_in[2];
    const float* conv_b     = (const float*)d_in[3];
    const float* x_proj_w   = (const float*)d_in[4];
    const float* dt_proj_w  = (const float*)d_in[5];
    const float* dt_proj_b  = (const float*)d_in[6];
    const float* A_log      = (const float*)d_in[7];
    const float* Dv         = (const float*)d_in[8];
    const float* out_proj_w = (const float*)d_in[9];
    float* out = (float*)d_out;
    float* ws  = (float*)d_ws;

    // workspace (float offsets):
    float* xzT    = ws;                        // [2048 e][2048 l] f32
    float* xpcT   = ws + 4194304;              // [1024][2048] f32
    float* xdblT  = ws + 6291456;              // [64][2048]   f32
    float* deltaT = ws + 6422528;              // [1024][2048] f32
    u16*   ypreT  = (u16*)(ws + 8519680);      // [1024][2048] bf16
    u16*   ypre   = (u16*)(ws + 9568256);      // [2048][1024] bf16
    u16*   xb     = (u16*)(ws + 10616832);     // [2048][512]  bf16
    u16*   w1b    = (u16*)(ws + 11141120);     // [2048][512]  bf16
    u16*   w2b    = (u16*)(ws + 11665408);     // [512][1024]  bf16

    // 0. cast x, in_proj_w, out_proj_w to bf16
    cast3_kernel<<<1280, 256, 0, stream>>>(x, in_proj_w, out_proj_w, xb, w1b, w2b);

    // 1. in_proj, transposed output: xzT = in_proj_w @ x^T  (64x64 tiles)
    gemm_mfma_nt<64, 64><<<dim3(2048 / 64, 2048 / 64), 256, 0, stream>>>(
        w1b, xb, xzT, 2 * D_INNER, L_SEQ, D_MODEL, L_SEQ);

    // 2. conv + silu on rows -> xpcT
    conv_rows_kernel<<<dim3(2, 1024), 256, 0, stream>>>(xzT, conv_w, conv_b, xpcT);

    // 3. x_proj -> xdblT
    xproj_kernel<<<256, 256, 0, stream>>>(xpcT, x_proj_w, xdblT);

    // 4. dt_proj + softplus -> deltaT
    deltaT_kernel<<<dim3(16, 16), 256, 0, stream>>>(xdblT, dt_proj_w, dt_proj_b,
                                                    deltaT);

    // 5. scan -> ypreT  (R12 scaffold + cumsum formulation)
    scan_kernel<<<512, 1024, 0, stream>>>(deltaT, xpcT, xzT, xdblT,
                                          A_log, Dv, ypreT);

    // 6. transpose ypreT -> ypre [l][d]
    trans_bf16_kernel<<<dim3(16, 32), 256, 0, stream>>>(ypreT, ypre);

    // 7. out_proj: 64x32 tiles -> 512 blocks
    gemm_mfma_nt<64, 32><<<dim3(512 / 32, 2048 / 64), 256, 0, stream>>>(
        ypre, w2b, out, L_SEQ, D_MODEL, D_INNER, D_MODEL);
}

// Round 17
// 159.992 us; speedup vs baseline: 1.0065x; 1.0065x over previous
//
#include <hip/hip_runtime.h>
#include <hip/hip_bf16.h>

// Problem constants (B=1)
#define L_SEQ   2048
#define D_MODEL 512
#define D_INNER 1024
#define D_STATE 16
#define DT_RANK 32

typedef unsigned short u16;
typedef short bf16x8 __attribute__((ext_vector_type(8)));
typedef float f32x4  __attribute__((ext_vector_type(4)));
typedef unsigned short u16x8 __attribute__((ext_vector_type(8)));

__device__ __forceinline__ u16 f2bf(float f) {
    union { float f; unsigned u; } x; x.f = f;
    unsigned r = x.u + 0x7FFFu + ((x.u >> 16) & 1u);
    return (u16)(r >> 16);
}

__device__ __forceinline__ void gload_lds16(const void* g, void* l) {
    __builtin_amdgcn_global_load_lds((const __attribute__((address_space(1))) void*)g,
                                     (__attribute__((address_space(3))) void*)l, 16, 0, 0);
}

// ---------------------------------------------------------------------------
// bf16 MFMA GEMM (NT):  C[m][n] = sum_k A[m*K+k]*B[n*K+k], C f32.  (verified)
// ---------------------------------------------------------------------------
template<int BM, int BN>
__global__ __launch_bounds__(256)
void gemm_mfma_nt(const u16* __restrict__ A, const u16* __restrict__ B,
                  float* __restrict__ C, int M, int N, int K, int ldc) {
    constexpr int FM = BM / 32;
    constexpr int FN = BN / 32;
    __shared__ u16 lA[BM * 64];
    __shared__ u16 lB[BN * 64];

    const int tid  = threadIdx.x;
    const int lane = tid & 63;
    const int w    = tid >> 6;
    const int wr   = w >> 1, wc = w & 1;
    const int m0 = blockIdx.y * BM;
    const int n0 = blockIdx.x * BN;

    f32x4 acc[FM][FN];
#pragma unroll
    for (int m = 0; m < FM; m++)
#pragma unroll
        for (int n = 0; n < FN; n++) acc[m][n] = (f32x4){0.f, 0.f, 0.f, 0.f};

    int offA[FM][2], offB[FN][2];
#pragma unroll
    for (int m = 0; m < FM; m++) {
        int r = wr * (BM / 2) + m * 16 + (lane & 15);
#pragma unroll
        for (int s = 0; s < 2; s++) {
            int kb = s * 4 + (lane >> 4);
            offA[m][s] = r * 128 + ((kb ^ (r & 7)) << 4);
        }
    }
#pragma unroll
    for (int n = 0; n < FN; n++) {
        int r = wc * (BN / 2) + n * 16 + (lane & 15);
#pragma unroll
        for (int s = 0; s < 2; s++) {
            int kb = s * 4 + (lane >> 4);
            offB[n][s] = r * 128 + ((kb ^ (r & 7)) << 4);
        }
    }

    const int ldsbase = (tid & 192) * 16;

    for (int k0 = 0; k0 < K; k0 += 64) {
        __syncthreads();
#pragma unroll
        for (int i = 0; i < BM / 32; i++) {
            int o = i * 4096 + tid * 16;
            int r = o >> 7;
            int kb = ((o >> 4) & 7) ^ (r & 7);
            gload_lds16(A + (size_t)(m0 + r) * K + k0 + kb * 8,
                        (char*)lA + i * 4096 + ldsbase);
        }
#pragma unroll
        for (int i = 0; i < BN / 32; i++) {
            int o = i * 4096 + tid * 16;
            int r = o >> 7;
            int kb = ((o >> 4) & 7) ^ (r & 7);
            gload_lds16(B + (size_t)(n0 + r) * K + k0 + kb * 8,
                        (char*)lB + i * 4096 + ldsbase);
        }
        __syncthreads();

#pragma unroll
        for (int s = 0; s < 2; s++) {
            bf16x8 av[FM], bv[FN];
#pragma unroll
            for (int m = 0; m < FM; m++)
                av[m] = *(const bf16x8*)((const char*)lA + offA[m][s]);
#pragma unroll
            for (int n = 0; n < FN; n++)
                bv[n] = *(const bf16x8*)((const char*)lB + offB[n][s]);
#pragma unroll
            for (int m = 0; m < FM; m++)
#pragma unroll
                for (int n = 0; n < FN; n++)
                    acc[m][n] = __builtin_amdgcn_mfma_f32_16x16x32_bf16(
                        av[m], bv[n], acc[m][n], 0, 0, 0);
        }
    }

    const int rb = (lane >> 4) * 4;
    const int cb = lane & 15;
#pragma unroll
    for (int m = 0; m < FM; m++)
#pragma unroll
        for (int n = 0; n < FN; n++) {
            int col = n0 + wc * (BN / 2) + n * 16 + cb;
#pragma unroll
            for (int j = 0; j < 4; j++) {
                int row = m0 + wr * (BM / 2) + m * 16 + rb + j;
                C[(size_t)row * ldc + col] = acc[m][n][j];
            }
        }
}

// ---------------------------------------------------------------------------
// Fused f32->bf16 cast of x, in_proj_w, out_proj_w.
// ---------------------------------------------------------------------------
__global__ __launch_bounds__(256)
void cast3_kernel(const float* __restrict__ x, const float* __restrict__ w1,
                  const float* __restrict__ w2,
                  u16* __restrict__ xb, u16* __restrict__ w1b, u16* __restrict__ w2b) {
    int g = blockIdx.x * 256 + threadIdx.x;
    const float* src; u16* dst; int off;
    if (g < 131072)      { src = x;  dst = xb;  off = g; }
    else if (g < 262144) { src = w1; dst = w1b; off = g - 131072; }
    else                 { src = w2; dst = w2b; off = g - 262144; }
    float4 v0 = ((const float4*)src)[off * 2];
    float4 v1 = ((const float4*)src)[off * 2 + 1];
    u16x8 r;
    r[0] = f2bf(v0.x); r[1] = f2bf(v0.y); r[2] = f2bf(v0.z); r[3] = f2bf(v0.w);
    r[4] = f2bf(v1.x); r[5] = f2bf(v1.y); r[6] = f2bf(v1.z); r[7] = f2bf(v1.w);
    *(u16x8*)(dst + (size_t)off * 8) = r;
}

// ---------------------------------------------------------------------------
// Causal depthwise conv (4 taps) + SiLU on T layout.
// ---------------------------------------------------------------------------
__global__ __launch_bounds__(256)
void conv_rows_kernel(const float* __restrict__ xzT,
                      const float* __restrict__ w,   // [1024][4]
                      const float* __restrict__ b,   // [1024]
                      float* __restrict__ xpcT) {
    const int d = blockIdx.y;
    const int l = blockIdx.x * 1024 + threadIdx.x * 4;
    const float4 wv = ((const float4*)w)[d];
    const float bias = b[d];
    const float* row = xzT + (size_t)d * L_SEQ;

    float4 cur  = *(const float4*)(row + l);
    float4 prev = (l == 0) ? make_float4(0.f, 0.f, 0.f, 0.f)
                           : *(const float4*)(row + l - 4);
    float e1 = prev.y, e2 = prev.z, e3 = prev.w;
    float e4 = cur.x, e5 = cur.y, e6 = cur.z, e7 = cur.w;
    float4 r;
    r.x = bias + wv.x * e1 + wv.y * e2 + wv.z * e3 + wv.w * e4;
    r.y = bias + wv.x * e2 + wv.y * e3 + wv.z * e4 + wv.w * e5;
    r.z = bias + wv.x * e3 + wv.y * e4 + wv.z * e5 + wv.w * e6;
    r.w = bias + wv.x * e4 + wv.y * e5 + wv.z * e6 + wv.w * e7;
    r.x = r.x / (1.f + __expf(-r.x));
    r.y = r.y / (1.f + __expf(-r.y));
    r.z = r.z / (1.f + __expf(-r.z));
    r.w = r.w / (1.f + __expf(-r.w));
    *(float4*)(xpcT + (size_t)d * L_SEQ + l) = r;
}

// ---------------------------------------------------------------------------
// x_proj on T layout.
// ---------------------------------------------------------------------------
__global__ __launch_bounds__(256)
void xproj_kernel(const float* __restrict__ xpcT,
                  const float* __restrict__ xw,    // [64][1024]
                  float* __restrict__ xdblT) {     // [64][2048]
    const int tid  = threadIdx.x;
    const int part = tid >> 7;
    const int e    = (tid >> 1) & 63;
    const int lc   = tid & 1;
    const int l0   = blockIdx.x * 8;

    const float* wrow = xw + (size_t)e * 1024 + part * 512;
    const float* xcol = xpcT + (size_t)part * 512 * L_SEQ + l0 + lc * 4;

    f32x4 acc = {0.f, 0.f, 0.f, 0.f};
#pragma unroll 4
    for (int k = 0; k < 512; k += 4) {
        float4 wv = *(const float4*)(wrow + k);
        f32x4 x0 = *(const f32x4*)(xcol + (size_t)(k + 0) * L_SEQ);
        f32x4 x1 = *(const f32x4*)(xcol + (size_t)(k + 1) * L_SEQ);
        f32x4 x2 = *(const f32x4*)(xcol + (size_t)(k + 2) * L_SEQ);
        f32x4 x3 = *(const f32x4*)(xcol + (size_t)(k + 3) * L_SEQ);
        acc += wv.x * x0 + wv.y * x1 + wv.z * x2 + wv.w * x3;
    }

    __shared__ f32x4 red[128];
    if (part == 1) red[(e << 1) | lc] = acc;
    __syncthreads();
    if (part == 0) {
        acc += red[(e << 1) | lc];
        *(f32x4*)(xdblT + (size_t)e * L_SEQ + l0 + lc * 4) = acc;
    }
}

// ---------------------------------------------------------------------------
// dt_proj + softplus (T layout).
// ---------------------------------------------------------------------------
__global__ __launch_bounds__(256)
void deltaT_kernel(const float* __restrict__ xdblT,
                   const float* __restrict__ dtw,   // [1024][32]
                   const float* __restrict__ dtb,
                   float* __restrict__ deltaT) {    // [1024][2048]
    const int tid = threadIdx.x;
    const int d0 = blockIdx.x * 64;
    const int l0 = blockIdx.y * 128;

    __shared__ float sx[32][128];
#pragma unroll
    for (int it = 0; it < 4; it++) {
        int idx = it * 256 + tid;
        int r  = idx >> 5;
        int c4 = (idx & 31) * 4;
        *(float4*)&sx[r][c4] = *(const float4*)(xdblT + (size_t)r * 2048 + l0 + c4);
    }

    const int dl = tid >> 2;
    const int lg = tid & 3;
    const int d  = d0 + dl;
    float wreg[32];
#pragma unroll
    for (int r4 = 0; r4 < 32; r4 += 4)
        *(float4*)&wreg[r4] = *(const float4*)(dtw + (size_t)d * 32 + r4);
    const float bias = dtb[d];
    __syncthreads();

#pragma unroll
    for (int j = 0; j < 8; j++) {
        float4 a = make_float4(bias, bias, bias, bias);
        const int col = j * 16 + lg * 4;
#pragma unroll
        for (int r = 0; r < 32; r++) {
            float4 v = *(const float4*)&sx[r][col];
            a.x = fmaf(wreg[r], v.x, a.x);
            a.y = fmaf(wreg[r], v.y, a.y);
            a.z = fmaf(wreg[r], v.z, a.z);
            a.w = fmaf(wreg[r], v.w, a.w);
        }
        float4 o;
        o.x = fmaxf(a.x, 0.f) + log1pf(expf(-fabsf(a.x)));
        o.y = fmaxf(a.y, 0.f) + log1pf(expf(-fabsf(a.y)));
        o.z = fmaxf(a.z, 0.f) + log1pf(expf(-fabsf(a.z)));
        o.w = fmaxf(a.w, 0.f) + log1pf(expf(-fabsf(a.w)));
        *(float4*)(deltaT + (size_t)d * 2048 + l0 + col) = o;
    }
}

// ---------------------------------------------------------------------------
// Chunked selective scan (R12, proven best — DO NOT TOUCH): 1024 thr,
// 2 ch/block, 512 blocks, 32 chunks x 64 steps, per-step shfl reduce,
// deferred-gate epilogue with staggered s_p[2][32][68].
// ---------------------------------------------------------------------------
#define NCHUNK 32

__global__ __launch_bounds__(1024)
void scan_kernel(const float* __restrict__ deltaT,
                 const float* __restrict__ xpcT,
                 const float* __restrict__ xzT,    // z rows at 1024+d
                 const float* __restrict__ xdblT,  // rows 32..47=B_T, 48..63=C_T
                 const float* __restrict__ A_log, const float* __restrict__ Dv,
                 u16* __restrict__ ypreT) {
    const int tid   = threadIdx.x;
    const int lane  = tid & 63;
    const int chunk = ((tid >> 6) << 1) | (lane >> 5);   // 0..31
    const int dl    = (lane >> 4) & 1;
    const int n     = lane & 15;
    const int li    = (dl << 4) | n;
    const int d0    = blockIdx.x * 2;
    const int d     = d0 + dl;
    const int lb    = chunk * 64;

    const float Aneg = -__expf(A_log[d * D_STATE + n]);

    const f32x4* dT4 = (const f32x4*)(deltaT + (size_t)d * L_SEQ + lb);
    const f32x4* xT4 = (const f32x4*)(xpcT   + (size_t)d * L_SEQ + lb);
    const f32x4* bT4 = (const f32x4*)(xdblT + (size_t)(32 + n) * L_SEQ + lb);
    const f32x4* cT4 = (const f32x4*)(xdblT + (size_t)(48 + n) * L_SEQ + lb);

    __shared__ float sLog[NCHUNK][32];
    __shared__ float sP[NCHUNK][32];
    __shared__ float sH[NCHUNK][32];
    __shared__ float s_p[2][NCHUNK][68];   // staggered rows (2-way = free)

    // ---- Phase A: chunk log-decay sum ----
    const float clipLog = -13.815511f;   // logf(1e-6f)
    float s = 0.f;
#pragma unroll 8
    for (int i = 0; i < 16; i++) {
        f32x4 d4 = dT4[i];
#pragma unroll
        for (int k = 0; k < 4; k++) s += fmaxf(d4[k] * Aneg, clipLog);
    }
    sLog[chunk][li] = s;
    sP[chunk][li]   = __expf(s);
    __syncthreads();

    float lsum = 0.f;
    for (int v = 0; v < chunk; v++) lsum += sLog[v][li];
    const float cAs = __expf(lsum);

    // ---- Phase B: local accumulation with known cA_start ----
    float hloc = 0.f, cA = cAs;
    for (int i = 0; i < 16; i++) {
        f32x4 d4 = dT4[i], x4 = xT4[i], b4 = bT4[i];
#pragma unroll
        for (int k = 0; k < 4; k++) {
            float dA = fmaxf(__expf(d4[k] * Aneg), 1e-6f);
            float g  = cA * __builtin_amdgcn_rcpf(cA + 1e-8f);
            hloc = dA * hloc + (dA * g) * (d4[k] * b4[k] * x4[k]);
            cA *= dA;
        }
    }
    sH[chunk][li] = hloc;
    __syncthreads();

    float h = 0.f;
    for (int v = 0; v < chunk; v++) h = sP[v][li] * h + sH[v][li];

    // ---- Phase C: full recurrence; masked path stores raw p only ----
    cA = cAs;
    for (int i = 0; i < 16; i++) {
        f32x4 d4 = dT4[i], x4 = xT4[i], b4 = bT4[i], c4 = cT4[i];
#pragma unroll
        for (int k = 0; k < 4; k++) {
            float dA = fmaxf(__expf(d4[k] * Aneg), 1e-6f);
            float g  = cA * __builtin_amdgcn_rcpf(cA + 1e-8f);
            h  = dA * h + (dA * g) * (d4[k] * b4[k] * x4[k]);
            cA *= dA;
            float p = h * c4[k];
            p += __shfl_xor(p, 1);
            p += __shfl_xor(p, 2);
            p += __shfl_xor(p, 4);
            p += __shfl_xor(p, 8);
            if (n == 0) s_p[dl][chunk][4 * i + k] = p;
        }
    }
    __syncthreads();

    // ---- Epilogue (all lanes, vectorized): y = (p + x*D) * silu(z) ----
    {
        const int rdl = tid >> 9;
        const int pos = (tid & 511) * 4;
        const int ck = pos >> 6, off = pos & 63;
        const float Ddr = Dv[d0 + rdl];
        f32x4 p4 = *(const f32x4*)&s_p[rdl][ck][off];
        f32x4 x4 = *(const f32x4*)(xpcT + (size_t)(d0 + rdl) * L_SEQ + pos);
        f32x4 z4 = *(const f32x4*)(xzT + (size_t)(1024 + d0 + rdl) * L_SEQ + pos);
        float y0 = (p4[0] + x4[0] * Ddr) * (z4[0] * __builtin_amdgcn_rcpf(1.f + __expf(-z4[0])));
        float y1 = (p4[1] + x4[1] * Ddr) * (z4[1] * __builtin_amdgcn_rcpf(1.f + __expf(-z4[1])));
        float y2 = (p4[2] + x4[2] * Ddr) * (z4[2] * __builtin_amdgcn_rcpf(1.f + __expf(-z4[2])));
        float y3 = (p4[3] + x4[3] * Ddr) * (z4[3] * __builtin_amdgcn_rcpf(1.f + __expf(-z4[3])));
        ushort4 o;
        o.x = f2bf(y0); o.y = f2bf(y1); o.z = f2bf(y2); o.w = f2bf(y3);
        *(ushort4*)(ypreT + (size_t)(d0 + rdl) * L_SEQ + pos) = o;
    }
}

// ---------------------------------------------------------------------------
// bf16 64x64 tile transpose: ypreT[1024 d][2048 l] -> ypre[2048 l][1024 d]
// ---------------------------------------------------------------------------
__global__ __launch_bounds__(256)
void trans_bf16_kernel(const u16* __restrict__ src, u16* __restrict__ dst) {
    __shared__ u16 t[64][72];
    const int d0 = blockIdx.x * 64, l0 = blockIdx.y * 64;
    const int r = threadIdx.x >> 3;
    const int c = (threadIdx.x & 7) * 8;
#pragma unroll
    for (int rr = r; rr < 64; rr += 32)
        *(u16x8*)&t[rr][c] = *(const u16x8*)(src + (size_t)(d0 + rr) * L_SEQ + l0 + c);
    __syncthreads();
#pragma unroll
    for (int rr = r; rr < 64; rr += 32) {
        u16x8 v;
#pragma unroll
        for (int j = 0; j < 8; j++) v[j] = t[c + j][rr];
        *(u16x8*)(dst + (size_t)(l0 + rr) * D_INNER + d0 + c) = v;
    }
}

// ---------------------------------------------------------------------------
extern "C" void kernel_launch(void* const* d_in, const int* in_sizes, int n_in,
                              void* d_out, int out_size, void* d_ws, size_t ws_size,
                              hipStream_t stream) {
    const float* x          = (const float*)d_in[0];
    const float* in_proj_w  = (const float*)d_in[1];
    const float* conv_w     = (const float*)d_in[2];
    const float* conv_b     = (const float*)d_in[3];
    const float* x_proj_w   = (const float*)d_in[4];
    const float* dt_proj_w  = (const float*)d_in[5];
    const float* dt_proj_b  = (const float*)d_in[6];
    const float* A_log      = (const float*)d_in[7];
    const float* Dv         = (const float*)d_in[8];
    const float* out_proj_w = (const float*)d_in[9];
    float* out = (float*)d_out;
    float* ws  = (float*)d_ws;

    // workspace (float offsets):
    float* xzT    = ws;                        // [2048 e][2048 l] f32
    float* xpcT   = ws + 4194304;              // [1024][2048] f32
    float* xdblT  = ws + 6291456;              // [64][2048]   f32
    float* deltaT = ws + 6422528;              // [1024][2048] f32
    u16*   ypreT  = (u16*)(ws + 8519680);      // [1024][2048] bf16
    u16*   ypre   = (u16*)(ws + 9568256);      // [2048][1024] bf16
    u16*   xb     = (u16*)(ws + 10616832);     // [2048][512]  bf16
    u16*   w1b    = (u16*)(ws + 11141120);     // [2048][512]  bf16
    u16*   w2b    = (u16*)(ws + 11665408);     // [512][1024]  bf16

    // 0. cast x, in_proj_w, out_proj_w to bf16
    cast3_kernel<<<1280, 256, 0, stream>>>(x, in_proj_w, out_proj_w, xb, w1b, w2b);

    // 1. in_proj, transposed output: xzT = in_proj_w @ x^T
    //    128x128 tiles (m93-proven ratio: 4x FLOPs per staged byte vs 64x64)
    gemm_mfma_nt<128, 128><<<dim3(2048 / 128, 2048 / 128), 256, 0, stream>>>(
        w1b, xb, xzT, 2 * D_INNER, L_SEQ, D_MODEL, L_SEQ);

    // 2. conv + silu on rows -> xpcT
    conv_rows_kernel<<<dim3(2, 1024), 256, 0, stream>>>(xzT, conv_w, conv_b, xpcT);

    // 3. x_proj -> xdblT
    xproj_kernel<<<256, 256, 0, stream>>>(xpcT, x_proj_w, xdblT);

    // 4. dt_proj + softplus -> deltaT
    deltaT_kernel<<<dim3(16, 16), 256, 0, stream>>>(xdblT, dt_proj_w, dt_proj_b,
                                                    deltaT);

    // 5. scan -> ypreT  (R12 config: proven best)
    scan_kernel<<<512, 1024, 0, stream>>>(deltaT, xpcT, xzT, xdblT,
                                          A_log, Dv, ypreT);

    // 6. transpose ypreT -> ypre [l][d]
    trans_bf16_kernel<<<dim3(16, 32), 256, 0, stream>>>(ypreT, ypre);

    // 7. out_proj: 64x32 tiles -> 512 blocks
    gemm_mfma_nt<64, 32><<<dim3(512 / 32, 2048 / 64), 256, 0, stream>>>(
        ypre, w2b, out, L_SEQ, D_MODEL, D_INNER, D_MODEL);
}

// Round 18
// 155.957 us; speedup vs baseline: 1.0325x; 1.0259x over previous
//
#include <hip/hip_runtime.h>
#include <hip/hip_bf16.h>

// Problem constants (B=1)
#define L_SEQ   2048
#define D_MODEL 512
#define D_INNER 1024
#define D_STATE 16
#define DT_RANK 32

typedef unsigned short u16;
typedef short bf16x8 __attribute__((ext_vector_type(8)));
typedef float f32x4  __attribute__((ext_vector_type(4)));
typedef unsigned short u16x8 __attribute__((ext_vector_type(8)));

__device__ __forceinline__ u16 f2bf(float f) {
    union { float f; unsigned u; } x; x.f = f;
    unsigned r = x.u + 0x7FFFu + ((x.u >> 16) & 1u);
    return (u16)(r >> 16);
}

__device__ __forceinline__ void gload_lds16(const void* g, void* l) {
    __builtin_amdgcn_global_load_lds((const __attribute__((address_space(1))) void*)g,
                                     (__attribute__((address_space(3))) void*)l, 16, 0, 0);
}

// ---------------------------------------------------------------------------
// bf16 MFMA GEMM (NT):  C[m][n] = sum_k A[m*K+k]*B[n*K+k], C f32.  (verified)
// ---------------------------------------------------------------------------
template<int BM, int BN>
__global__ __launch_bounds__(256)
void gemm_mfma_nt(const u16* __restrict__ A, const u16* __restrict__ B,
                  float* __restrict__ C, int M, int N, int K, int ldc) {
    constexpr int FM = BM / 32;
    constexpr int FN = BN / 32;
    __shared__ u16 lA[BM * 64];
    __shared__ u16 lB[BN * 64];

    const int tid  = threadIdx.x;
    const int lane = tid & 63;
    const int w    = tid >> 6;
    const int wr   = w >> 1, wc = w & 1;
    const int m0 = blockIdx.y * BM;
    const int n0 = blockIdx.x * BN;

    f32x4 acc[FM][FN];
#pragma unroll
    for (int m = 0; m < FM; m++)
#pragma unroll
        for (int n = 0; n < FN; n++) acc[m][n] = (f32x4){0.f, 0.f, 0.f, 0.f};

    int offA[FM][2], offB[FN][2];
#pragma unroll
    for (int m = 0; m < FM; m++) {
        int r = wr * (BM / 2) + m * 16 + (lane & 15);
#pragma unroll
        for (int s = 0; s < 2; s++) {
            int kb = s * 4 + (lane >> 4);
            offA[m][s] = r * 128 + ((kb ^ (r & 7)) << 4);
        }
    }
#pragma unroll
    for (int n = 0; n < FN; n++) {
        int r = wc * (BN / 2) + n * 16 + (lane & 15);
#pragma unroll
        for (int s = 0; s < 2; s++) {
            int kb = s * 4 + (lane >> 4);
            offB[n][s] = r * 128 + ((kb ^ (r & 7)) << 4);
        }
    }

    const int ldsbase = (tid & 192) * 16;

    for (int k0 = 0; k0 < K; k0 += 64) {
        __syncthreads();
#pragma unroll
        for (int i = 0; i < BM / 32; i++) {
            int o = i * 4096 + tid * 16;
            int r = o >> 7;
            int kb = ((o >> 4) & 7) ^ (r & 7);
            gload_lds16(A + (size_t)(m0 + r) * K + k0 + kb * 8,
                        (char*)lA + i * 4096 + ldsbase);
        }
#pragma unroll
        for (int i = 0; i < BN / 32; i++) {
            int o = i * 4096 + tid * 16;
            int r = o >> 7;
            int kb = ((o >> 4) & 7) ^ (r & 7);
            gload_lds16(B + (size_t)(n0 + r) * K + k0 + kb * 8,
                        (char*)lB + i * 4096 + ldsbase);
        }
        __syncthreads();

#pragma unroll
        for (int s = 0; s < 2; s++) {
            bf16x8 av[FM], bv[FN];
#pragma unroll
            for (int m = 0; m < FM; m++)
                av[m] = *(const bf16x8*)((const char*)lA + offA[m][s]);
#pragma unroll
            for (int n = 0; n < FN; n++)
                bv[n] = *(const bf16x8*)((const char*)lB + offB[n][s]);
#pragma unroll
            for (int m = 0; m < FM; m++)
#pragma unroll
                for (int n = 0; n < FN; n++)
                    acc[m][n] = __builtin_amdgcn_mfma_f32_16x16x32_bf16(
                        av[m], bv[n], acc[m][n], 0, 0, 0);
        }
    }

    const int rb = (lane >> 4) * 4;
    const int cb = lane & 15;
#pragma unroll
    for (int m = 0; m < FM; m++)
#pragma unroll
        for (int n = 0; n < FN; n++) {
            int col = n0 + wc * (BN / 2) + n * 16 + cb;
#pragma unroll
            for (int j = 0; j < 4; j++) {
                int row = m0 + wr * (BM / 2) + m * 16 + rb + j;
                C[(size_t)row * ldc + col] = acc[m][n][j];
            }
        }
}

// ---------------------------------------------------------------------------
// Fused f32->bf16 cast of x, in_proj_w, out_proj_w.
// ---------------------------------------------------------------------------
__global__ __launch_bounds__(256)
void cast3_kernel(const float* __restrict__ x, const float* __restrict__ w1,
                  const float* __restrict__ w2,
                  u16* __restrict__ xb, u16* __restrict__ w1b, u16* __restrict__ w2b) {
    int g = blockIdx.x * 256 + threadIdx.x;
    const float* src; u16* dst; int off;
    if (g < 131072)      { src = x;  dst = xb;  off = g; }
    else if (g < 262144) { src = w1; dst = w1b; off = g - 131072; }
    else                 { src = w2; dst = w2b; off = g - 262144; }
    float4 v0 = ((const float4*)src)[off * 2];
    float4 v1 = ((const float4*)src)[off * 2 + 1];
    u16x8 r;
    r[0] = f2bf(v0.x); r[1] = f2bf(v0.y); r[2] = f2bf(v0.z); r[3] = f2bf(v0.w);
    r[4] = f2bf(v1.x); r[5] = f2bf(v1.y); r[6] = f2bf(v1.z); r[7] = f2bf(v1.w);
    *(u16x8*)(dst + (size_t)off * 8) = r;
}

// ---------------------------------------------------------------------------
// Causal depthwise conv (4 taps) + SiLU on T layout.
// ---------------------------------------------------------------------------
__global__ __launch_bounds__(256)
void conv_rows_kernel(const float* __restrict__ xzT,
                      const float* __restrict__ w,   // [1024][4]
                      const float* __restrict__ b,   // [1024]
                      float* __restrict__ xpcT) {
    const int d = blockIdx.y;
    const int l = blockIdx.x * 1024 + threadIdx.x * 4;
    const float4 wv = ((const float4*)w)[d];
    const float bias = b[d];
    const float* row = xzT + (size_t)d * L_SEQ;

    float4 cur  = *(const float4*)(row + l);
    float4 prev = (l == 0) ? make_float4(0.f, 0.f, 0.f, 0.f)
                           : *(const float4*)(row + l - 4);
    float e1 = prev.y, e2 = prev.z, e3 = prev.w;
    float e4 = cur.x, e5 = cur.y, e6 = cur.z, e7 = cur.w;
    float4 r;
    r.x = bias + wv.x * e1 + wv.y * e2 + wv.z * e3 + wv.w * e4;
    r.y = bias + wv.x * e2 + wv.y * e3 + wv.z * e4 + wv.w * e5;
    r.z = bias + wv.x * e3 + wv.y * e4 + wv.z * e5 + wv.w * e6;
    r.w = bias + wv.x * e4 + wv.y * e5 + wv.z * e6 + wv.w * e7;
    r.x = r.x / (1.f + __expf(-r.x));
    r.y = r.y / (1.f + __expf(-r.y));
    r.z = r.z / (1.f + __expf(-r.z));
    r.w = r.w / (1.f + __expf(-r.w));
    *(float4*)(xpcT + (size_t)d * L_SEQ + l) = r;
}

// ---------------------------------------------------------------------------
// x_proj on T layout.
// ---------------------------------------------------------------------------
__global__ __launch_bounds__(256)
void xproj_kernel(const float* __restrict__ xpcT,
                  const float* __restrict__ xw,    // [64][1024]
                  float* __restrict__ xdblT) {     // [64][2048]
    const int tid  = threadIdx.x;
    const int part = tid >> 7;
    const int e    = (tid >> 1) & 63;
    const int lc   = tid & 1;
    const int l0   = blockIdx.x * 8;

    const float* wrow = xw + (size_t)e * 1024 + part * 512;
    const float* xcol = xpcT + (size_t)part * 512 * L_SEQ + l0 + lc * 4;

    f32x4 acc = {0.f, 0.f, 0.f, 0.f};
#pragma unroll 4
    for (int k = 0; k < 512; k += 4) {
        float4 wv = *(const float4*)(wrow + k);
        f32x4 x0 = *(const f32x4*)(xcol + (size_t)(k + 0) * L_SEQ);
        f32x4 x1 = *(const f32x4*)(xcol + (size_t)(k + 1) * L_SEQ);
        f32x4 x2 = *(const f32x4*)(xcol + (size_t)(k + 2) * L_SEQ);
        f32x4 x3 = *(const f32x4*)(xcol + (size_t)(k + 3) * L_SEQ);
        acc += wv.x * x0 + wv.y * x1 + wv.z * x2 + wv.w * x3;
    }

    __shared__ f32x4 red[128];
    if (part == 1) red[(e << 1) | lc] = acc;
    __syncthreads();
    if (part == 0) {
        acc += red[(e << 1) | lc];
        *(f32x4*)(xdblT + (size_t)e * L_SEQ + l0 + lc * 4) = acc;
    }
}

// ---------------------------------------------------------------------------
// dt_proj + softplus (T layout).
// ---------------------------------------------------------------------------
__global__ __launch_bounds__(256)
void deltaT_kernel(const float* __restrict__ xdblT,
                   const float* __restrict__ dtw,   // [1024][32]
                   const float* __restrict__ dtb,
                   float* __restrict__ deltaT) {    // [1024][2048]
    const int tid = threadIdx.x;
    const int d0 = blockIdx.x * 64;
    const int l0 = blockIdx.y * 128;

    __shared__ float sx[32][128];
#pragma unroll
    for (int it = 0; it < 4; it++) {
        int idx = it * 256 + tid;
        int r  = idx >> 5;
        int c4 = (idx & 31) * 4;
        *(float4*)&sx[r][c4] = *(const float4*)(xdblT + (size_t)r * 2048 + l0 + c4);
    }

    const int dl = tid >> 2;
    const int lg = tid & 3;
    const int d  = d0 + dl;
    float wreg[32];
#pragma unroll
    for (int r4 = 0; r4 < 32; r4 += 4)
        *(float4*)&wreg[r4] = *(const float4*)(dtw + (size_t)d * 32 + r4);
    const float bias = dtb[d];
    __syncthreads();

#pragma unroll
    for (int j = 0; j < 8; j++) {
        float4 a = make_float4(bias, bias, bias, bias);
        const int col = j * 16 + lg * 4;
#pragma unroll
        for (int r = 0; r < 32; r++) {
            float4 v = *(const float4*)&sx[r][col];
            a.x = fmaf(wreg[r], v.x, a.x);
            a.y = fmaf(wreg[r], v.y, a.y);
            a.z = fmaf(wreg[r], v.z, a.z);
            a.w = fmaf(wreg[r], v.w, a.w);
        }
        float4 o;
        o.x = fmaxf(a.x, 0.f) + log1pf(expf(-fabsf(a.x)));
        o.y = fmaxf(a.y, 0.f) + log1pf(expf(-fabsf(a.y)));
        o.z = fmaxf(a.z, 0.f) + log1pf(expf(-fabsf(a.z)));
        o.w = fmaxf(a.w, 0.f) + log1pf(expf(-fabsf(a.w)));
        *(float4*)(deltaT + (size_t)d * 2048 + l0 + col) = o;
    }
}

// ---------------------------------------------------------------------------
// Chunked selective scan (R12, proven best): 1024 thr, 2 ch/block, 512
// blocks, 32 chunks x 64 steps, per-step shfl reduce, deferred-gate epilogue
// with staggered s_p[2][32][68].  7 structural alternatives tried and
// falsified (R10/R11/R13/R14/R16) — latency-bound local optimum.
// ---------------------------------------------------------------------------
#define NCHUNK 32

__global__ __launch_bounds__(1024)
void scan_kernel(const float* __restrict__ deltaT,
                 const float* __restrict__ xpcT,
                 const float* __restrict__ xzT,    // z rows at 1024+d
                 const float* __restrict__ xdblT,  // rows 32..47=B_T, 48..63=C_T
                 const float* __restrict__ A_log, const float* __restrict__ Dv,
                 u16* __restrict__ ypreT) {
    const int tid   = threadIdx.x;
    const int lane  = tid & 63;
    const int chunk = ((tid >> 6) << 1) | (lane >> 5);   // 0..31
    const int dl    = (lane >> 4) & 1;
    const int n     = lane & 15;
    const int li    = (dl << 4) | n;
    const int d0    = blockIdx.x * 2;
    const int d     = d0 + dl;
    const int lb    = chunk * 64;

    const float Aneg = -__expf(A_log[d * D_STATE + n]);

    const f32x4* dT4 = (const f32x4*)(deltaT + (size_t)d * L_SEQ + lb);
    const f32x4* xT4 = (const f32x4*)(xpcT   + (size_t)d * L_SEQ + lb);
    const f32x4* bT4 = (const f32x4*)(xdblT + (size_t)(32 + n) * L_SEQ + lb);
    const f32x4* cT4 = (const f32x4*)(xdblT + (size_t)(48 + n) * L_SEQ + lb);

    __shared__ float sLog[NCHUNK][32];
    __shared__ float sP[NCHUNK][32];
    __shared__ float sH[NCHUNK][32];
    __shared__ float s_p[2][NCHUNK][68];   // staggered rows (2-way = free)

    // ---- Phase A: chunk log-decay sum ----
    const float clipLog = -13.815511f;   // logf(1e-6f)
    float s = 0.f;
#pragma unroll 8
    for (int i = 0; i < 16; i++) {
        f32x4 d4 = dT4[i];
#pragma unroll
        for (int k = 0; k < 4; k++) s += fmaxf(d4[k] * Aneg, clipLog);
    }
    sLog[chunk][li] = s;
    sP[chunk][li]   = __expf(s);
    __syncthreads();

    float lsum = 0.f;
    for (int v = 0; v < chunk; v++) lsum += sLog[v][li];
    const float cAs = __expf(lsum);

    // ---- Phase B: local accumulation with known cA_start ----
    float hloc = 0.f, cA = cAs;
    for (int i = 0; i < 16; i++) {
        f32x4 d4 = dT4[i], x4 = xT4[i], b4 = bT4[i];
#pragma unroll
        for (int k = 0; k < 4; k++) {
            float dA = fmaxf(__expf(d4[k] * Aneg), 1e-6f);
            float g  = cA * __builtin_amdgcn_rcpf(cA + 1e-8f);
            hloc = dA * hloc + (dA * g) * (d4[k] * b4[k] * x4[k]);
            cA *= dA;
        }
    }
    sH[chunk][li] = hloc;
    __syncthreads();

    float h = 0.f;
    for (int v = 0; v < chunk; v++) h = sP[v][li] * h + sH[v][li];

    // ---- Phase C: full recurrence; masked path stores raw p only ----
    cA = cAs;
    for (int i = 0; i < 16; i++) {
        f32x4 d4 = dT4[i], x4 = xT4[i], b4 = bT4[i], c4 = cT4[i];
#pragma unroll
        for (int k = 0; k < 4; k++) {
            float dA = fmaxf(__expf(d4[k] * Aneg), 1e-6f);
            float g  = cA * __builtin_amdgcn_rcpf(cA + 1e-8f);
            h  = dA * h + (dA * g) * (d4[k] * b4[k] * x4[k]);
            cA *= dA;
            float p = h * c4[k];
            p += __shfl_xor(p, 1);
            p += __shfl_xor(p, 2);
            p += __shfl_xor(p, 4);
            p += __shfl_xor(p, 8);
            if (n == 0) s_p[dl][chunk][4 * i + k] = p;
        }
    }
    __syncthreads();

    // ---- Epilogue (all lanes, vectorized): y = (p + x*D) * silu(z) ----
    {
        const int rdl = tid >> 9;
        const int pos = (tid & 511) * 4;
        const int ck = pos >> 6, off = pos & 63;
        const float Ddr = Dv[d0 + rdl];
        f32x4 p4 = *(const f32x4*)&s_p[rdl][ck][off];
        f32x4 x4 = *(const f32x4*)(xpcT + (size_t)(d0 + rdl) * L_SEQ + pos);
        f32x4 z4 = *(const f32x4*)(xzT + (size_t)(1024 + d0 + rdl) * L_SEQ + pos);
        float y0 = (p4[0] + x4[0] * Ddr) * (z4[0] * __builtin_amdgcn_rcpf(1.f + __expf(-z4[0])));
        float y1 = (p4[1] + x4[1] * Ddr) * (z4[1] * __builtin_amdgcn_rcpf(1.f + __expf(-z4[1])));
        float y2 = (p4[2] + x4[2] * Ddr) * (z4[2] * __builtin_amdgcn_rcpf(1.f + __expf(-z4[2])));
        float y3 = (p4[3] + x4[3] * Ddr) * (z4[3] * __builtin_amdgcn_rcpf(1.f + __expf(-z4[3])));
        ushort4 o;
        o.x = f2bf(y0); o.y = f2bf(y1); o.z = f2bf(y2); o.w = f2bf(y3);
        *(ushort4*)(ypreT + (size_t)(d0 + rdl) * L_SEQ + pos) = o;
    }
}

// ---------------------------------------------------------------------------
// bf16 64x64 tile transpose: ypreT[1024 d][2048 l] -> ypre[2048 l][1024 d]
// ---------------------------------------------------------------------------
__global__ __launch_bounds__(256)
void trans_bf16_kernel(const u16* __restrict__ src, u16* __restrict__ dst) {
    __shared__ u16 t[64][72];
    const int d0 = blockIdx.x * 64, l0 = blockIdx.y * 64;
    const int r = threadIdx.x >> 3;
    const int c = (threadIdx.x & 7) * 8;
#pragma unroll
    for (int rr = r; rr < 64; rr += 32)
        *(u16x8*)&t[rr][c] = *(const u16x8*)(src + (size_t)(d0 + rr) * L_SEQ + l0 + c);
    __syncthreads();
#pragma unroll
    for (int rr = r; rr < 64; rr += 32) {
        u16x8 v;
#pragma unroll
        for (int j = 0; j < 8; j++) v[j] = t[c + j][rr];
        *(u16x8*)(dst + (size_t)(l0 + rr) * D_INNER + d0 + c) = v;
    }
}

// ---------------------------------------------------------------------------
extern "C" void kernel_launch(void* const* d_in, const int* in_sizes, int n_in,
                              void* d_out, int out_size, void* d_ws, size_t ws_size,
                              hipStream_t stream) {
    const float* x          = (const float*)d_in[0];
    const float* in_proj_w  = (const float*)d_in[1];
    const float* conv_w     = (const float*)d_in[2];
    const float* conv_b     = (const float*)d_in[3];
    const float* x_proj_w   = (const float*)d_in[4];
    const float* dt_proj_w  = (const float*)d_in[5];
    const float* dt_proj_b  = (const float*)d_in[6];
    const float* A_log      = (const float*)d_in[7];
    const float* Dv         = (const float*)d_in[8];
    const float* out_proj_w = (const float*)d_in[9];
    float* out = (float*)d_out;
    float* ws  = (float*)d_ws;

    // workspace (float offsets):
    float* xzT    = ws;                        // [2048 e][2048 l] f32
    float* xpcT   = ws + 4194304;              // [1024][2048] f32
    float* xdblT  = ws + 6291456;              // [64][2048]   f32
    float* deltaT = ws + 6422528;              // [1024][2048] f32
    u16*   ypreT  = (u16*)(ws + 8519680);      // [1024][2048] bf16
    u16*   ypre   = (u16*)(ws + 9568256);      // [2048][1024] bf16
    u16*   xb     = (u16*)(ws + 10616832);     // [2048][512]  bf16
    u16*   w1b    = (u16*)(ws + 11141120);     // [2048][512]  bf16
    u16*   w2b    = (u16*)(ws + 11665408);     // [512][1024]  bf16

    // 0. cast x, in_proj_w, out_proj_w to bf16
    cast3_kernel<<<1280, 256, 0, stream>>>(x, in_proj_w, out_proj_w, xb, w1b, w2b);

    // 1. in_proj, transposed output: xzT = in_proj_w @ x^T  (64x64 tiles —
    //    R17 showed 128x128 is neutral-to-worse at K=512 with this structure)
    gemm_mfma_nt<64, 64><<<dim3(2048 / 64, 2048 / 64), 256, 0, stream>>>(
        w1b, xb, xzT, 2 * D_INNER, L_SEQ, D_MODEL, L_SEQ);

    // 2. conv + silu on rows -> xpcT
    conv_rows_kernel<<<dim3(2, 1024), 256, 0, stream>>>(xzT, conv_w, conv_b, xpcT);

    // 3. x_proj -> xdblT
    xproj_kernel<<<256, 256, 0, stream>>>(xpcT, x_proj_w, xdblT);

    // 4. dt_proj + softplus -> deltaT
    deltaT_kernel<<<dim3(16, 16), 256, 0, stream>>>(xdblT, dt_proj_w, dt_proj_b,
                                                    deltaT);

    // 5. scan -> ypreT  (R12 config: proven best)
    scan_kernel<<<512, 1024, 0, stream>>>(deltaT, xpcT, xzT, xdblT,
                                          A_log, Dv, ypreT);

    // 6. transpose ypreT -> ypre [l][d]
    trans_bf16_kernel<<<dim3(16, 32), 256, 0, stream>>>(ypreT, ypre);

    // 7. out_proj: 64x32 tiles -> 512 blocks
    gemm_mfma_nt<64, 32><<<dim3(512 / 32, 2048 / 64), 256, 0, stream>>>(
        ypre, w2b, out, L_SEQ, D_MODEL, D_INNER, D_MODEL);
}